// Round 6
// baseline (205.844 us; speedup 1.0000x reference)
//
#include <hip/hip_runtime.h>
#include <hip/hip_bf16.h>
#include <stdint.h>

using bf16   = __bf16;
using bf16x4 = __attribute__((ext_vector_type(4))) __bf16;
using bf16x8 = __attribute__((ext_vector_type(8))) __bf16;
using f32x4  = __attribute__((ext_vector_type(4))) float;

#define NN  2048   // nodes
#define DD  16     // embedding dim
#define BB  64     // batch
#define CC  64     // channels (in == out)
#define BCC 4096   // BB*CC
#define GNODE 2    // nodes per k_node block (fallback path)

// ---------------- K1: A = softmax(relu(E E^T)) row-wise, bf16 out ----------
__global__ __launch_bounds__(256) void k_softmax(const float* __restrict__ E,
                                                 bf16* __restrict__ A) {
  const int n = blockIdx.x;
  const int t = threadIdx.x;
  float en[DD];
#pragma unroll
  for (int d = 0; d < DD; ++d) en[d] = E[(size_t)n * DD + d];

  float r[8];
  float mx = 0.0f;
#pragma unroll
  for (int j = 0; j < 8; ++j) {
    const int m = t + 256 * j;
    const float4* ep = (const float4*)(E + (size_t)m * DD);
    float4 p0 = ep[0], p1 = ep[1], p2 = ep[2], p3 = ep[3];
    float s = p0.x*en[0] + p0.y*en[1] + p0.z*en[2] + p0.w*en[3]
            + p1.x*en[4] + p1.y*en[5] + p1.z*en[6] + p1.w*en[7]
            + p2.x*en[8] + p2.y*en[9] + p2.z*en[10] + p2.w*en[11]
            + p3.x*en[12] + p3.y*en[13] + p3.z*en[14] + p3.w*en[15];
    s = fmaxf(s, 0.0f);
    r[j] = s;
    mx = fmaxf(mx, s);
  }
  __shared__ float red[256];
  red[t] = mx;
  __syncthreads();
  for (int off = 128; off > 0; off >>= 1) {
    if (t < off) red[t] = fmaxf(red[t], red[t + off]);
    __syncthreads();
  }
  mx = red[0];
  __syncthreads();
  float ex[8], sum = 0.0f;
#pragma unroll
  for (int j = 0; j < 8; ++j) { ex[j] = __expf(r[j] - mx); sum += ex[j]; }
  red[t] = sum;
  __syncthreads();
  for (int off = 128; off > 0; off >>= 1) {
    if (t < off) red[t] += red[t + off];
    __syncthreads();
  }
  const float inv = 1.0f / red[0];
#pragma unroll
  for (int j = 0; j < 8; ++j)
    A[(size_t)n * NN + t + 256 * j] = (bf16)(ex[j] * inv);
}

// ---------------- generic bf16 transpose: in[R][C] -> out[C][R] ------------
__global__ __launch_bounds__(256) void k_transpose(const bf16* __restrict__ in,
                                                   bf16* __restrict__ out,
                                                   int R, int C) {
  __shared__ bf16 tile[64 * 68];
  const int bx = blockIdx.x, by = blockIdx.y;
  const int t = threadIdx.x;
  const int r0 = by * 64, c0 = bx * 64;
#pragma unroll
  for (int j = 0; j < 16; ++j) {
    const int q = t + 256 * j;
    const int r = q >> 6, c = q & 63;
    tile[r * 68 + c] = in[(size_t)(r0 + r) * C + c0 + c];
  }
  __syncthreads();
#pragma unroll
  for (int j = 0; j < 16; ++j) {
    const int q = t + 256 * j;
    const int rr = q >> 6, cc = q & 63;
    out[(size_t)(c0 + rr) * R + r0 + cc] = tile[cc * 68 + rr];
  }
}

// ---------------- K3: XrT[b*64+i][m] = bf16(x[b][m][i]) --------------------
__global__ __launch_bounds__(256) void k_build_xrt(const float* __restrict__ x,
                                                   bf16* __restrict__ XrT) {
  __shared__ bf16 tile[64 * 68];  // [m][i]
  const int b = blockIdx.x;
  const int m0 = blockIdx.y * 64;
  const int t = threadIdx.x;
#pragma unroll
  for (int j = 0; j < 16; ++j) {
    const int q = t + 256 * j;
    const int m = q >> 6, i = q & 63;
    tile[m * 68 + i] = (bf16)x[((size_t)b * NN + m0 + m) * CC + i];
  }
  __syncthreads();
#pragma unroll
  for (int j = 0; j < 16; ++j) {
    const int q = t + 256 * j;
    const int i = q >> 6, m = q & 63;
    XrT[((size_t)b * CC + i) * NN + m0 + m] = tile[m * 68 + i];
  }
}

// ---------------- K4 (fallback): WpT[r][o][d] bf16, r = kc*64+i ------------
__global__ __launch_bounds__(256) void k_prep_wpt(const float* __restrict__ Wp,
                                                  bf16* __restrict__ WpT) {
  const int e = blockIdx.x * 256 + threadIdx.x;  // 0..12287 = r*64+o
  const int r = e >> 6, o = e & 63;
  const size_t src = (size_t)(r >> 6) * 4096 + (size_t)(r & 63) * 64 + o;
#pragma unroll
  for (int d = 0; d < DD; ++d)
    WpT[(size_t)e * DD + d] = (bf16)Wp[(size_t)d * 12288 + src];
}

// ---------------- GEMM (B^T form): C[m][n] = sum_k L[m][k]*R[n][k] ---------
// 128x128 tile, BK=64, 4 waves (2x2), 4x4 16x16x32 MFMA tiles per wave.
// T3-min 2-phase: double-buffered LDS, stage(t+1) issued BEFORE compute(t),
// raw s_barrier + counted vmcnt(8) so next-tile loads stay in flight.
// T1: XCD-aware bijective block swizzle (nwg % 8 == 0 for our grids).
// EPI==2: C = 2*acc - Xext  (xg2 epilogue; Xext is x [b][rg][i], cg=b*64+i).
template <int EPI>
__global__ __launch_bounds__(256) void k_gemm_bt(const bf16* __restrict__ L,
                                                 const bf16* __restrict__ R,
                                                 bf16* __restrict__ C,
                                                 int M, int Nc, int K,
                                                 const float* __restrict__ Xext) {
  __shared__ uint4 lds[4096];  // 2 bufs x (1024 L + 1024 R) 16B units = 64 KB
  const int t = threadIdx.x;
  const int lane = t & 63, w = t >> 6;
  const int wm = w & 1, wn = w >> 1;
  const int h = lane >> 4;

  // T1 swizzle: contiguous chunks of the flat grid per XCD
  const int nwg = gridDim.x * gridDim.y;
  const int bid = blockIdx.y * gridDim.x + blockIdx.x;
  const int cpx = nwg >> 3;
  const int swz = (bid & 7) * cpx + (bid >> 3);
  const int bx = swz % gridDim.x, by = swz / gridDim.x;

  const int m0 = by * 128, n0 = bx * 128;

  f32x4 acc[4][4];
  const f32x4 zz = {0.f, 0.f, 0.f, 0.f};
#pragma unroll
  for (int mt = 0; mt < 4; ++mt)
#pragma unroll
    for (int nt = 0; nt < 4; ++nt) acc[mt][nt] = zz;

  // stage one 128x64 L-tile + R-tile into buffer `buf` (8 gload_lds/thread)
  auto stage = [&](int buf, int kt) {
    uint4* base = lds + buf * 2048;
#pragma unroll
    for (int c = 0; c < 4; ++c) {
      const int q = t + 256 * c;          // 0..1023 linear LDS unit
      const int row = q >> 3, col4 = q & 7;
      const int scol = col4 ^ (row & 7);
      const bf16* srcL = L + (size_t)(m0 + row) * K + kt + (scol << 3);
      const bf16* srcR = R + (size_t)(n0 + row) * K + kt + (scol << 3);
      __builtin_amdgcn_global_load_lds(srcL, &base[q & ~63], 16, 0, 0);
      __builtin_amdgcn_global_load_lds(srcR, &base[1024 + (q & ~63)], 16, 0, 0);
    }
  };

  auto compute = [&](int buf) {
    const bf16x8* Lsv = (const bf16x8*)(lds + buf * 2048);
    const bf16x8* Rsv = (const bf16x8*)(lds + buf * 2048 + 1024);
#pragma unroll
    for (int kk = 0; kk < 2; ++kk) {
      bf16x8 af[4], bfr[4];
#pragma unroll
      for (int mt = 0; mt < 4; ++mt) {
        const int row = wm * 64 + mt * 16 + (lane & 15);
        af[mt] = Lsv[(row << 3) | ((kk * 4 + h) ^ (row & 7))];
      }
#pragma unroll
      for (int nt = 0; nt < 4; ++nt) {
        const int row = wn * 64 + nt * 16 + (lane & 15);
        bfr[nt] = Rsv[(row << 3) | ((kk * 4 + h) ^ (row & 7))];
      }
#pragma unroll
      for (int mt = 0; mt < 4; ++mt)
#pragma unroll
        for (int nt = 0; nt < 4; ++nt)
          acc[mt][nt] = __builtin_amdgcn_mfma_f32_16x16x32_bf16(
              af[mt], bfr[nt], acc[mt][nt], 0, 0, 0);
    }
  };

  const int NT = K >> 6;
  stage(0, 0);
  int cur = 0;
  for (int ts = 0; ts < NT - 1; ++ts) {
    stage(cur ^ 1, (ts + 1) << 6);               // 8 vm ops in flight
    asm volatile("s_waitcnt vmcnt(8)" ::: "memory");  // prev tile landed
    __builtin_amdgcn_s_barrier();
    __builtin_amdgcn_sched_barrier(0);
    compute(cur);
    __builtin_amdgcn_s_barrier();                // readers done before overwrite
    __builtin_amdgcn_sched_barrier(0);
    cur ^= 1;
  }
  asm volatile("s_waitcnt vmcnt(0)" ::: "memory");
  __builtin_amdgcn_s_barrier();
  __builtin_amdgcn_sched_barrier(0);
  compute(cur);

  // epilogue: C/D layout col = lane&15, row = 4*(lane>>4)+r
#pragma unroll
  for (int mt = 0; mt < 4; ++mt)
#pragma unroll
    for (int nt = 0; nt < 4; ++nt)
#pragma unroll
      for (int r = 0; r < 4; ++r) {
        const int rg = m0 + wm * 64 + mt * 16 + 4 * h + r;
        const int cg = n0 + wn * 64 + nt * 16 + (lane & 15);
        float v = acc[mt][nt][r];
        if (EPI == 2) {
          const int b = cg >> 6, i = cg & 63;
          v = 2.0f * v - Xext[(((size_t)b * NN + rg) * CC) + i];
        }
        C[(size_t)rg * Nc + cg] = (bf16)v;
      }
}

// ---------------- K5a: materialize per-node weights, pre-swizzled ----------
// Wsw[n] = 1536 16B-units; unit q = o*24 + (u&~7) + ((u&7)^(o&7)) holds
// W[n][r=u*8+j][o], j=0..7, where W[n][r][o] = sum_d E[n,d]*Wp[d][r>>6][r&63][o].
// Each thread owns half a unit (4 r) with its 4x16 Wp slice in registers,
// loops over nodes -> Wp read ~once, writes perfectly coalesced.
__global__ __launch_bounds__(256) void k_wgen(const float* __restrict__ Wp,
                                              const float* __restrict__ E,
                                              bf16* __restrict__ Wsw,
                                              int nbase) {
  const int t = threadIdx.x;
  const int uglob = blockIdx.x * 128 + (t >> 1);   // 0..1535
  const int half  = t & 1;
  const int o   = uglob / 24;
  const int usw = uglob - o * 24;
  const int u   = (usw & ~7) | ((usw & 7) ^ (o & 7));  // logical k-unit
  const int rb  = u * 8 + half * 4;

  float wreg[4][DD];
#pragma unroll
  for (int j = 0; j < 4; ++j) {
    const int r = rb + j;
    const int k = r >> 6, i = r & 63;
#pragma unroll
    for (int d = 0; d < DD; ++d)
      wreg[j][d] = Wp[(((size_t)d * 3 + k) * 64 + i) * 64 + o];
  }

  const int nloc0 = blockIdx.y * 32;
  for (int ii = 0; ii < 32; ++ii) {
    const int ln = nloc0 + ii;
    const float* ep = E + (size_t)(nbase + ln) * DD;
    float en[DD];
#pragma unroll
    for (int d = 0; d < DD; ++d) en[d] = ep[d];
    bf16x4 outv;
#pragma unroll
    for (int j = 0; j < 4; ++j) {
      float a = 0.0f;
#pragma unroll
      for (int d = 0; d < DD; ++d) a += en[d] * wreg[j][d];
      outv[j] = (bf16)a;
    }
    *(bf16x4*)(Wsw + (size_t)ln * 12288 + uglob * 8 + half * 4) = outv;
  }
}

// ---------------- K5b: apply — stage Wsw via global_load_lds + MFMA --------
__global__ __launch_bounds__(256) void k_apply(const float* __restrict__ x,
                                               const float* __restrict__ E,
                                               const bf16* __restrict__ Wsw,
                                               const float* __restrict__ bp,
                                               const bf16* __restrict__ xg1,
                                               const bf16* __restrict__ xg2,
                                               float* __restrict__ out,
                                               int nbase) {
  __shared__ uint4 lds[1536];  // 24 KB, one node's weights (pre-swizzled)
  const int t = threadIdx.x;
  const int lane = t & 63, w = t >> 6;
  const int h = lane >> 4, l16 = lane & 15;
  const int ln = blockIdx.x;
  const int n = nbase + ln;
  const int b = w * 16 + l16;

  // T14 prefetch: all apply-phase operands to regs before the staging wait
  float4 xa[4];
  bf16x8 xgr[4];
  {
    const float* xb = x + ((size_t)b * NN + n) * CC;
    xa[0] = *(const float4*)(xb + h * 8);
    xa[1] = *(const float4*)(xb + h * 8 + 4);
    xa[2] = *(const float4*)(xb + 32 + h * 8);
    xa[3] = *(const float4*)(xb + 32 + h * 8 + 4);
    const bf16* x1 = xg1 + (size_t)n * BCC + b * CC;
    const bf16* x2 = xg2 + (size_t)n * BCC + b * CC;
    xgr[0] = *(const bf16x8*)(x1 + h * 8);
    xgr[1] = *(const bf16x8*)(x1 + 32 + h * 8);
    xgr[2] = *(const bf16x8*)(x2 + h * 8);
    xgr[3] = *(const bf16x8*)(x2 + 32 + h * 8);
  }

  // stage this node's 24 KB of weights, linear (already swizzled in memory)
#pragma unroll
  for (int c = 0; c < 6; ++c) {
    const int q = t + 256 * c;   // 0..1535
    const bf16* src = Wsw + (size_t)ln * 12288 + q * 8;
    __builtin_amdgcn_global_load_lds(src, &lds[q & ~63], 16, 0, 0);
  }

  float en[DD];
#pragma unroll
  for (int d = 0; d < DD; ++d) en[d] = E[(size_t)n * DD + d];
  float bias_v[4];
#pragma unroll
  for (int nt = 0; nt < 4; ++nt) {
    const int o = nt * 16 + l16;
    float a = 0.0f;
#pragma unroll
    for (int d = 0; d < DD; ++d) a += en[d] * bp[d * CC + o];
    bias_v[nt] = a;
  }

  __syncthreads();  // drains vmcnt for global_load_lds

  const bf16x8* Wv = (const bf16x8*)lds;
  f32x4 acc[4];
  const f32x4 zz = {0.f, 0.f, 0.f, 0.f};
#pragma unroll
  for (int nt = 0; nt < 4; ++nt) acc[nt] = zz;

#pragma unroll
  for (int s = 0; s < 6; ++s) {
    bf16x8 af;
    if (s < 2) {
      const float4 u4 = xa[s * 2], v4 = xa[s * 2 + 1];
      af[0] = (bf16)u4.x; af[1] = (bf16)u4.y; af[2] = (bf16)u4.z; af[3] = (bf16)u4.w;
      af[4] = (bf16)v4.x; af[5] = (bf16)v4.y; af[6] = (bf16)v4.z; af[7] = (bf16)v4.w;
    } else {
      af = xgr[s - 2];
    }
    const int u = s * 4 + h;
#pragma unroll
    for (int nt = 0; nt < 4; ++nt) {
      const int o = nt * 16 + l16;
      const bf16x8 bfr = Wv[o * 24 + (u & ~7) + ((u & 7) ^ (o & 7))];
      acc[nt] = __builtin_amdgcn_mfma_f32_16x16x32_bf16(af, bfr, acc[nt], 0, 0, 0);
    }
  }
#pragma unroll
  for (int nt = 0; nt < 4; ++nt) {
    const int o = nt * 16 + l16;
#pragma unroll
    for (int r = 0; r < 4; ++r) {
      const int br = w * 16 + 4 * h + r;
      out[((size_t)br * NN + n) * CC + o] = acc[nt][r] + bias_v[nt];
    }
  }
}

// ---------------- K5 (fallback): 2 nodes/block fused gen+apply -------------
__global__ __launch_bounds__(256) void k_node(const float* __restrict__ x,
                                              const float* __restrict__ E,
                                              const bf16* __restrict__ WpT,
                                              const float* __restrict__ bp,
                                              const bf16* __restrict__ xg1,
                                              const bf16* __restrict__ xg2,
                                              float* __restrict__ out) {
  __shared__ alignas(16) bf16 sW[GNODE * 1536 * 8];  // 48 KB
  const int t = threadIdx.x;
  const int lane = t & 63, w = t >> 6;
  const int h = lane >> 4, l16 = lane & 15;
  const int n0 = blockIdx.x * GNODE;
  const int b = w * 16 + l16;

  float4  xa[GNODE][4];
  bf16x8  xgr[GNODE][4];
#pragma unroll
  for (int g = 0; g < GNODE; ++g) {
    const int n = n0 + g;
    const float* xb = x + ((size_t)b * NN + n) * CC;
    xa[g][0] = *(const float4*)(xb + h * 8);
    xa[g][1] = *(const float4*)(xb + h * 8 + 4);
    xa[g][2] = *(const float4*)(xb + 32 + h * 8);
    xa[g][3] = *(const float4*)(xb + 32 + h * 8 + 4);
    const bf16* x1 = xg1 + (size_t)n * BCC + b * CC;
    const bf16* x2 = xg2 + (size_t)n * BCC + b * CC;
    xgr[g][0] = *(const bf16x8*)(x1 + h * 8);
    xgr[g][1] = *(const bf16x8*)(x1 + 32 + h * 8);
    xgr[g][2] = *(const bf16x8*)(x2 + h * 8);
    xgr[g][3] = *(const bf16x8*)(x2 + 32 + h * 8);
  }

  float en[GNODE][DD];
#pragma unroll
  for (int g = 0; g < GNODE; ++g)
#pragma unroll
    for (int d = 0; d < DD; ++d) en[g][d] = E[(size_t)(n0 + g) * DD + d];

  float bias_v[GNODE][4];
#pragma unroll
  for (int g = 0; g < GNODE; ++g)
#pragma unroll
    for (int nt = 0; nt < 4; ++nt) {
      const int o = nt * 16 + l16;
      float a = 0.0f;
#pragma unroll
      for (int d = 0; d < DD; ++d) a += en[g][d] * bp[d * CC + o];
      bias_v[g][nt] = a;
    }

#pragma unroll
  for (int c = 0; c < 6; ++c) {
    const int idx = t + 256 * c;
    const int o = idx & 63;
    const int u = idx >> 6;
    const bf16* src = WpT + ((size_t)(u * 8) * 64 + o) * DD;
    bf16x8 wv[GNODE];
#pragma unroll
    for (int j = 0; j < 8; ++j) {
      const bf16x8* wr = (const bf16x8*)(src + (size_t)j * 64 * DD);
      bf16x8 w0 = wr[0], w1 = wr[1];
      float wf[DD];
#pragma unroll
      for (int d = 0; d < 8; ++d) { wf[d] = (float)w0[d]; wf[8 + d] = (float)w1[d]; }
#pragma unroll
      for (int g = 0; g < GNODE; ++g) {
        float a = 0.0f;
#pragma unroll
        for (int d = 0; d < DD; ++d) a += en[g][d] * wf[d];
        wv[g][j] = (bf16)a;
      }
    }
    const int swz = o * 24 + (u & ~7) + ((u & 7) ^ (o & 7));
#pragma unroll
    for (int g = 0; g < GNODE; ++g)
      *(bf16x8*)(sW + (size_t)(g * 1536 + swz) * 8) = wv[g];
  }
  __syncthreads();

#pragma unroll
  for (int g = 0; g < GNODE; ++g) {
    f32x4 acc[4];
    const f32x4 zz = {0.f, 0.f, 0.f, 0.f};
#pragma unroll
    for (int nt = 0; nt < 4; ++nt) acc[nt] = zz;
#pragma unroll
    for (int s = 0; s < 6; ++s) {
      bf16x8 af;
      if (s < 2) {
        const float4 u4 = xa[g][s * 2], v4 = xa[g][s * 2 + 1];
        af[0] = (bf16)u4.x; af[1] = (bf16)u4.y; af[2] = (bf16)u4.z; af[3] = (bf16)u4.w;
        af[4] = (bf16)v4.x; af[5] = (bf16)v4.y; af[6] = (bf16)v4.z; af[7] = (bf16)v4.w;
      } else {
        af = xgr[g][s - 2];
      }
      const int u = s * 4 + h;
#pragma unroll
      for (int nt = 0; nt < 4; ++nt) {
        const int o = nt * 16 + l16;
        const bf16x8 bfr = *(const bf16x8*)(
            sW + (size_t)(g * 1536 + o * 24 + (u & ~7) + ((u & 7) ^ (o & 7))) * 8);
        acc[nt] = __builtin_amdgcn_mfma_f32_16x16x32_bf16(af, bfr, acc[nt], 0, 0, 0);
      }
    }
#pragma unroll
    for (int nt = 0; nt < 4; ++nt) {
      const int o = nt * 16 + l16;
#pragma unroll
      for (int r = 0; r < 4; ++r) {
        const int br = w * 16 + 4 * h + r;
        out[((size_t)br * NN + (n0 + g)) * CC + o] = acc[nt][r] + bias_v[g][nt];
      }
    }
  }
}

extern "C" void kernel_launch(void* const* d_in, const int* in_sizes, int n_in,
                              void* d_out, int out_size, void* d_ws, size_t ws_size,
                              hipStream_t stream) {
  const float* x  = (const float*)d_in[0];   // [64,2048,64]
  const float* E  = (const float*)d_in[1];   // [2048,16]
  const float* Wp = (const float*)d_in[2];   // [16,3,64,64]
  const float* bp = (const float*)d_in[3];   // [16,64]
  float* out = (float*)d_out;                // [64,2048,64]

  char* ws = (char*)d_ws;
  const size_t MB = (size_t)1 << 20;
  const bool big = ws_size >= 88 * MB;

  if (big) {
    // A:0-8 | T(XrT/Xg1T):8-24 | xg1:56-72 | xg2:72-88 | Wsw:0-50.33 (after GEMM2)
    bf16* A    = (bf16*)(ws);
    bf16* XrT  = (bf16*)(ws + 8 * MB);
    bf16* Xg1T = XrT;
    bf16* xg1  = (bf16*)(ws + 56 * MB);
    bf16* xg2  = (bf16*)(ws + 72 * MB);
    bf16* Wsw  = (bf16*)(ws);          // overlays dead A+T after GEMM2

    k_softmax<<<NN, 256, 0, stream>>>(E, A);
    k_build_xrt<<<dim3(64, 32), 256, 0, stream>>>(x, XrT);
    k_gemm_bt<0><<<dim3(32, 16), 256, 0, stream>>>(A, XrT, xg1, NN, BCC, NN, nullptr);
    k_transpose<<<dim3(64, 32), 256, 0, stream>>>(xg1, Xg1T, NN, BCC);
    k_gemm_bt<2><<<dim3(32, 16), 256, 0, stream>>>(A, Xg1T, xg2, NN, BCC, NN, x);
    k_wgen<<<dim3(12, NN / 32), 256, 0, stream>>>(Wp, E, Wsw, 0);
    k_apply<<<NN, 256, 0, stream>>>(x, E, Wsw, bp, xg1, xg2, out, 0);
  } else {
    // fallback (proven R5 path): A:0-8 | T:8-24 | xg1:24-40 | xg2:40-56 | WpT:56+
    bf16* A    = (bf16*)(ws);
    bf16* XrT  = (bf16*)(ws + 8 * MB);
    bf16* Xg1T = XrT;
    bf16* xg1  = (bf16*)(ws + 24 * MB);
    bf16* xg2  = (bf16*)(ws + 40 * MB);
    bf16* WpT  = (bf16*)(ws + 56 * MB);

    k_softmax<<<NN, 256, 0, stream>>>(E, A);
    k_build_xrt<<<dim3(64, 32), 256, 0, stream>>>(x, XrT);
    k_prep_wpt<<<48, 256, 0, stream>>>(Wp, WpT);
    k_gemm_bt<0><<<dim3(32, 16), 256, 0, stream>>>(A, XrT, xg1, NN, BCC, NN, nullptr);
    k_transpose<<<dim3(64, 32), 256, 0, stream>>>(xg1, Xg1T, NN, BCC);
    k_gemm_bt<2><<<dim3(32, 16), 256, 0, stream>>>(A, Xg1T, xg2, NN, BCC, NN, x);
    k_node<<<NN / GNODE, 256, 0, stream>>>(x, E, WpT, bp, xg1, xg2, out);
  }
}